// Round 1
// baseline (538.584 us; speedup 1.0000x reference)
//
#include <hip/hip_runtime.h>

#define NNODES 50000
#define NEDGES 800000
#define ETOT   (NNODES + NEDGES)   // 850000 (edges + self loops)
#define NEG 0.2f

// ---------------- CSR build (by destination) ----------------
__global__ void hist_kernel(const int* __restrict__ ei, int* __restrict__ deg) {
  int i = blockIdx.x * blockDim.x + threadIdx.x;
  if (i >= ETOT) return;
  int dst = (i < NEDGES) ? ei[NEDGES + i] : (i - NEDGES);
  atomicAdd(&deg[dst], 1);
}

__global__ void scan_kernel(const int* __restrict__ deg, int* __restrict__ rowptr) {
  __shared__ int buf[1024];
  __shared__ int carry;
  if (threadIdx.x == 0) carry = 0;
  __syncthreads();
  for (int base = 0; base < NNODES; base += 1024) {
    int i = base + (int)threadIdx.x;
    int v = (i < NNODES) ? deg[i] : 0;
    int sum = v;
    buf[threadIdx.x] = v;
    __syncthreads();
    for (int off = 1; off < 1024; off <<= 1) {
      int t = (threadIdx.x >= (unsigned)off) ? buf[threadIdx.x - off] : 0;
      __syncthreads();
      sum += t;
      buf[threadIdx.x] = sum;
      __syncthreads();
    }
    int c = carry;
    if (i < NNODES) rowptr[i] = c + sum - v;   // exclusive prefix
    __syncthreads();
    if (threadIdx.x == 1023) carry = c + buf[1023];
    __syncthreads();
  }
  if (threadIdx.x == 0) rowptr[NNODES] = carry;   // == ETOT
}

__global__ void scatter_kernel(const int* __restrict__ ei, const int* __restrict__ rowptr,
                               int* __restrict__ fill, int* __restrict__ csrc) {
  int i = blockIdx.x * blockDim.x + threadIdx.x;
  if (i >= ETOT) return;
  int src, dst;
  if (i < NEDGES) { src = ei[i]; dst = ei[NEDGES + i]; }
  else            { src = i - NEDGES; dst = src; }
  int pos = rowptr[dst] + atomicAdd(&fill[dst], 1);
  csrc[pos] = src;
}

// ---------------- fused dual GEMM: G1 = A@W1+b1, G2 = A@W2+b2 (K=128) ----------------
template<int MCOLS>
__global__ void dual_gemm(const float* __restrict__ A,
                          const float* __restrict__ W1, const float* __restrict__ b1,
                          const float* __restrict__ W2, const float* __restrict__ b2,
                          float* __restrict__ G1, float* __restrict__ G2) {
  constexpr int K = 128;
  constexpr int ROWS = 32;
  constexpr int TC = 2 * MCOLS;          // total output cols (both mats)
  constexpr int GROUPS = 256 / TC;       // row groups sharing the column set
  constexpr int RPG = ROWS / GROUPS;     // rows per group
  __shared__ __align__(16) float As[ROWS][K];
  int row0 = blockIdx.x * ROWS;
  for (int idx = threadIdx.x; idx < ROWS * K; idx += 256) {
    int r = idx >> 7, k = idx & 127;
    int g = row0 + r;
    As[r][k] = (g < NNODES) ? A[(size_t)g * K + k] : 0.f;
  }
  __syncthreads();
  int t = threadIdx.x;
  int colid = t % TC;
  int grp = t / TC;
  const float* Wp; const float* bp; float* Gp; int col;
  if (colid < MCOLS) { Wp = W1; bp = b1; Gp = G1; col = colid; }
  else               { Wp = W2; bp = b2; Gp = G2; col = colid - MCOLS; }
  float acc[RPG];
#pragma unroll
  for (int r = 0; r < RPG; ++r) acc[r] = 0.f;
  for (int k4 = 0; k4 < K / 4; ++k4) {
    float w0 = Wp[(4 * k4 + 0) * MCOLS + col];
    float w1 = Wp[(4 * k4 + 1) * MCOLS + col];
    float w2 = Wp[(4 * k4 + 2) * MCOLS + col];
    float w3 = Wp[(4 * k4 + 3) * MCOLS + col];
#pragma unroll
    for (int r = 0; r < RPG; ++r) {
      float4 a = *(const float4*)&As[grp * RPG + r][4 * k4];
      acc[r] = fmaf(a.x, w0, acc[r]);
      acc[r] = fmaf(a.y, w1, acc[r]);
      acc[r] = fmaf(a.z, w2, acc[r]);
      acc[r] = fmaf(a.w, w3, acc[r]);
    }
  }
  float bias = bp[col];
#pragma unroll
  for (int r = 0; r < RPG; ++r) {
    int g = row0 + grp * RPG + r;
    if (g < NNODES) Gp[(size_t)g * MCOLS + col] = acc[r] + bias;
  }
}

// ---------------- layer 1: 4 heads x 32 ch, online segment softmax, fused bias+ELU ----------------
// one wave per node; lane handles channels (2*lane, 2*lane+1); head = lane>>4
__global__ void gat1_edge(const int* __restrict__ rowptr, const int* __restrict__ csrc,
                          const float* __restrict__ gl, const float* __restrict__ gr,
                          const float* __restrict__ att, const float* __restrict__ bias,
                          float* __restrict__ hout) {
  int node = blockIdx.x * 4 + (threadIdx.x >> 6);
  if (node >= NNODES) return;
  int lane = threadIdx.x & 63;
  int c0 = lane * 2;
  float2 av  = *(const float2*)(att + c0);
  float2 grd = *(const float2*)(gr + (size_t)node * 128 + c0);
  int start = rowptr[node], end = rowptr[node + 1];
  float m = -3.4e38f, denom = 0.f, a0 = 0.f, a1 = 0.f;
  for (int p = start; p < end; ++p) {
    int s = csrc[p];
    float2 g = *(const float2*)(gl + (size_t)s * 128 + c0);
    float m0 = g.x + grd.x; m0 = m0 > 0.f ? m0 : NEG * m0;
    float m1 = g.y + grd.y; m1 = m1 > 0.f ? m1 : NEG * m1;
    float v = av.x * m0 + av.y * m1;
    v += __shfl_xor(v, 1); v += __shfl_xor(v, 2);
    v += __shfl_xor(v, 4); v += __shfl_xor(v, 8);   // e[head], broadcast in 16-lane group
    float nm = fmaxf(m, v);
    float corr = __expf(m - nm);
    float ex   = __expf(v - nm);
    denom = denom * corr + ex;
    a0 = a0 * corr + ex * g.x;
    a1 = a1 * corr + ex * g.y;
    m = nm;
  }
  float2 bv = *(const float2*)(bias + c0);
  float o0 = a0 / denom + bv.x;
  float o1 = a1 / denom + bv.y;
  o0 = o0 > 0.f ? o0 : __expf(o0) - 1.f;   // ELU
  o1 = o1 > 0.f ? o1 : __expf(o1) - 1.f;
  *(float2*)(hout + (size_t)node * 128 + c0) = make_float2(o0, o1);
}

// ---------------- layer 2: 1 head x 32 ch ----------------
// one wave per node; lane -> channel (lane&31), two edge slots (lane>>5)
__global__ void gat2_edge(const int* __restrict__ rowptr, const int* __restrict__ csrc,
                          const float* __restrict__ gl, const float* __restrict__ gr,
                          const float* __restrict__ att, const float* __restrict__ bias,
                          float* __restrict__ out) {
  int node = blockIdx.x * 4 + (threadIdx.x >> 6);
  if (node >= NNODES) return;
  int lane = threadIdx.x & 63;
  int c = lane & 31;
  int slot = lane >> 5;
  float attc = att[c];
  float grd = gr[(size_t)node * 32 + c];
  int start = rowptr[node], end = rowptr[node + 1];
  float m = -3.4e38f, denom = 0.f, acc = 0.f;
  for (int p = start + slot; p < end; p += 2) {
    int s = csrc[p];
    float g = gl[(size_t)s * 32 + c];
    float t = g + grd; t = t > 0.f ? t : NEG * t;
    float v = attc * t;
    v += __shfl_xor(v, 1); v += __shfl_xor(v, 2); v += __shfl_xor(v, 4);
    v += __shfl_xor(v, 8); v += __shfl_xor(v, 16);  // e, broadcast in 32-lane half
    float nm = fmaxf(m, v);
    float corr = __expf(m - nm);
    float ex   = __expf(v - nm);
    denom = denom * corr + ex;
    acc   = acc * corr + ex * g;
    m = nm;
  }
  // combine the two slots
  float mo = __shfl_xor(m, 32);
  float nm = fmaxf(m, mo);
  float corr = __expf(m - nm);        // 0 if this slot was empty (m = -3.4e38)
  float d = denom * corr;
  float a = acc * corr;
  d += __shfl_xor(d, 32);
  a += __shfl_xor(a, 32);
  if (slot == 0) out[(size_t)node * 32 + c] = a / d + bias[c];
}

extern "C" void kernel_launch(void* const* d_in, const int* in_sizes, int n_in,
                              void* d_out, int out_size, void* d_ws, size_t ws_size,
                              hipStream_t stream) {
  const float* x     = (const float*)d_in[0];
  const int*   ei    = (const int*)  d_in[1];
  const float* Wl1   = (const float*)d_in[2];
  const float* bl1   = (const float*)d_in[3];
  const float* Wr1   = (const float*)d_in[4];
  const float* br1   = (const float*)d_in[5];
  const float* att1  = (const float*)d_in[6];
  const float* bias1 = (const float*)d_in[7];
  const float* Wl2   = (const float*)d_in[8];
  const float* bl2   = (const float*)d_in[9];
  const float* Wr2   = (const float*)d_in[10];
  const float* br2   = (const float*)d_in[11];
  const float* att2  = (const float*)d_in[12];
  const float* bias2 = (const float*)d_in[13];
  float* out = (float*)d_out;

  char* w = (char*)d_ws;
  auto carve = [&](size_t bytes) {
    char* p = w;
    w += (bytes + 255) & ~(size_t)255;
    return p;
  };
  float* gl1 = (float*)carve((size_t)NNODES * 128 * 4);
  float* gr1 = (float*)carve((size_t)NNODES * 128 * 4);
  float* h   = (float*)carve((size_t)NNODES * 128 * 4);
  float* gl2 = (float*)carve((size_t)NNODES * 32 * 4);
  float* gr2 = (float*)carve((size_t)NNODES * 32 * 4);
  int* deg    = (int*)carve((size_t)NNODES * 4);
  int* fill   = (int*)carve((size_t)NNODES * 4);
  int* rowptr = (int*)carve((size_t)(NNODES + 1) * 4);
  int* csrc   = (int*)carve((size_t)ETOT * 4);

  hipMemsetAsync(deg, 0, (size_t)NNODES * 4, stream);
  hipMemsetAsync(fill, 0, (size_t)NNODES * 4, stream);

  hist_kernel<<<(ETOT + 255) / 256, 256, 0, stream>>>(ei, deg);
  scan_kernel<<<1, 1024, 0, stream>>>(deg, rowptr);
  scatter_kernel<<<(ETOT + 255) / 256, 256, 0, stream>>>(ei, rowptr, fill, csrc);

  dual_gemm<128><<<(NNODES + 31) / 32, 256, 0, stream>>>(x, Wl1, bl1, Wr1, br1, gl1, gr1);
  gat1_edge<<<(NNODES + 3) / 4, 256, 0, stream>>>(rowptr, csrc, gl1, gr1, att1, bias1, h);
  dual_gemm<32><<<(NNODES + 31) / 32, 256, 0, stream>>>(h, Wl2, bl2, Wr2, br2, gl2, gr2);
  gat2_edge<<<(NNODES + 3) / 4, 256, 0, stream>>>(rowptr, csrc, gl2, gr2, att2, bias2, out);
}

// Round 2
// 518.216 us; speedup vs baseline: 1.0393x; 1.0393x over previous
//
#include <hip/hip_runtime.h>

#define NNODES 50000
#define NEDGES 800000
#define ETOT   (NNODES + NEDGES)   // 850000 (edges + self loops)
#define NEG 0.2f

// ---------------- CSR build (by destination) ----------------
__global__ void hist_kernel(const int* __restrict__ ei, int* __restrict__ deg) {
  int i = blockIdx.x * blockDim.x + threadIdx.x;
  if (i >= ETOT) return;
  int dst = (i < NEDGES) ? ei[NEDGES + i] : (i - NEDGES);
  atomicAdd(&deg[dst], 1);
}

// 1024 threads, thread-serial chunks + shuffle scan (2 barriers total)
#define SCHUNK 49
__global__ __launch_bounds__(1024) void scan_kernel(const int* __restrict__ deg,
                                                    int* __restrict__ rowptr) {
  int t = threadIdx.x;
  int lo = t * SCHUNK;
  int hi = lo + SCHUNK; if (hi > NNODES) hi = NNODES;
  int sum = 0;
  for (int i = lo; i < hi; ++i) sum += deg[i];
  int lane = t & 63, wv = t >> 6;          // 16 waves
  int v = sum;
  for (int off = 1; off < 64; off <<= 1) {
    int u = __shfl_up(v, off);
    if (lane >= off) v += u;               // inclusive wave scan
  }
  __shared__ int wsum[16], woff[16];
  if (lane == 63) wsum[wv] = v;
  __syncthreads();
  if (t == 0) { int r = 0; for (int i = 0; i < 16; ++i) { woff[i] = r; r += wsum[i]; } }
  __syncthreads();
  int run = woff[wv] + v - sum;            // exclusive prefix for this thread's chunk
  for (int i = lo; i < hi; ++i) { rowptr[i] = run; run += deg[i]; }
  if (t == 0) rowptr[NNODES] = ETOT;
}

__global__ void scatter_kernel(const int* __restrict__ ei, const int* __restrict__ rowptr,
                               int* __restrict__ fill, int* __restrict__ csrc) {
  int i = blockIdx.x * blockDim.x + threadIdx.x;
  if (i >= ETOT) return;
  int src, dst;
  if (i < NEDGES) { src = ei[i]; dst = ei[NEDGES + i]; }
  else            { src = i - NEDGES; dst = src; }
  int pos = rowptr[dst] + atomicAdd(&fill[dst], 1);
  csrc[pos] = src;
}

// ---------------- fused dual GEMM: G1 = A@W1+b1, G2 = A@W2+b2 (K=128) ----------------
// each thread owns column `col` of BOTH W1 and W2 (shares As reads); no spilling.
template<int MCOLS>
__global__ __launch_bounds__(256) void dual_gemm(const float* __restrict__ A,
                          const float* __restrict__ W1, const float* __restrict__ b1,
                          const float* __restrict__ W2, const float* __restrict__ b2,
                          float* __restrict__ G1, float* __restrict__ G2) {
  constexpr int K = 128;
  constexpr int ROWS = 16;
  constexpr int GROUPS = 256 / MCOLS;    // 2 (MCOLS=128) or 8 (MCOLS=32)
  constexpr int RPG = ROWS / GROUPS;     // 8 or 2
  __shared__ __align__(16) float As[ROWS][K];
  int row0 = blockIdx.x * ROWS;
  for (int idx = threadIdx.x; idx < ROWS * (K / 4); idx += 256) {
    int r = idx >> 5, k4 = idx & 31;
    int g = row0 + r;
    float4 val = (g < NNODES) ? *(const float4*)&A[(size_t)g * K + 4 * k4]
                              : make_float4(0.f, 0.f, 0.f, 0.f);
    *(float4*)&As[r][4 * k4] = val;
  }
  __syncthreads();
  int col = threadIdx.x % MCOLS;
  int grp = threadIdx.x / MCOLS;
  float acc1[RPG], acc2[RPG];
#pragma unroll
  for (int r = 0; r < RPG; ++r) { acc1[r] = 0.f; acc2[r] = 0.f; }
  for (int k4 = 0; k4 < K / 4; ++k4) {
    float w1v[4], w2v[4];
#pragma unroll
    for (int j = 0; j < 4; ++j) {
      w1v[j] = W1[(size_t)(4 * k4 + j) * MCOLS + col];
      w2v[j] = W2[(size_t)(4 * k4 + j) * MCOLS + col];
    }
#pragma unroll
    for (int r = 0; r < RPG; ++r) {
      float4 a = *(const float4*)&As[grp * RPG + r][4 * k4];
      acc1[r] = fmaf(a.x, w1v[0], acc1[r]);
      acc1[r] = fmaf(a.y, w1v[1], acc1[r]);
      acc1[r] = fmaf(a.z, w1v[2], acc1[r]);
      acc1[r] = fmaf(a.w, w1v[3], acc1[r]);
      acc2[r] = fmaf(a.x, w2v[0], acc2[r]);
      acc2[r] = fmaf(a.y, w2v[1], acc2[r]);
      acc2[r] = fmaf(a.z, w2v[2], acc2[r]);
      acc2[r] = fmaf(a.w, w2v[3], acc2[r]);
    }
  }
  float bb1 = b1[col], bb2 = b2[col];
#pragma unroll
  for (int r = 0; r < RPG; ++r) {
    int g = row0 + grp * RPG + r;
    if (g < NNODES) {
      G1[(size_t)g * MCOLS + col] = acc1[r] + bb1;
      G2[(size_t)g * MCOLS + col] = acc2[r] + bb2;
    }
  }
}

// ---------------- layer 1: block per node, 4 waves split edges, online softmax ----------------
__global__ __launch_bounds__(256) void gat1_edge(const int* __restrict__ rowptr,
                          const int* __restrict__ csrc,
                          const float* __restrict__ gl, const float* __restrict__ gr,
                          const float* __restrict__ att, const float* __restrict__ bias,
                          float* __restrict__ hout) {
  int node = blockIdx.x;
  int t = threadIdx.x;
  int lane = t & 63, w = t >> 6;
  int c0 = lane * 2;
  float2 av  = *(const float2*)(att + c0);
  float2 grd = *(const float2*)(gr + (size_t)node * 128 + c0);
  int start = rowptr[node], end = rowptr[node + 1];
  float m = -3.4e38f, denom = 0.f, a0 = 0.f, a1 = 0.f;
  int p = start + w;
  int s = (p < end) ? csrc[p] : 0;
  float2 g = (p < end) ? *(const float2*)(gl + (size_t)s * 128 + c0)
                       : make_float2(0.f, 0.f);
  while (p < end) {
    int pn = p + 4;
    int sn = (pn < end) ? csrc[pn] : 0;
    float2 gn = (pn < end) ? *(const float2*)(gl + (size_t)sn * 128 + c0)
                           : make_float2(0.f, 0.f);
    float m0 = g.x + grd.x; m0 = m0 > 0.f ? m0 : NEG * m0;
    float m1 = g.y + grd.y; m1 = m1 > 0.f ? m1 : NEG * m1;
    float v = av.x * m0 + av.y * m1;
    v += __shfl_xor(v, 1); v += __shfl_xor(v, 2);
    v += __shfl_xor(v, 4); v += __shfl_xor(v, 8);   // e[head] across 16-lane head group
    float nm = fmaxf(m, v);
    float corr = __expf(m - nm);
    float ex   = __expf(v - nm);
    denom = denom * corr + ex;
    a0 = a0 * corr + ex * g.x;
    a1 = a1 * corr + ex * g.y;
    m = nm;
    g = gn; p = pn;
  }
  __shared__ float4 red[4][64];
  red[w][lane] = make_float4(m, denom, a0, a1);
  __syncthreads();
  if (w == 0) {
    float4 r0 = red[0][lane], r1 = red[1][lane], r2 = red[2][lane], r3 = red[3][lane];
    float nm = fmaxf(fmaxf(r0.x, r1.x), fmaxf(r2.x, r3.x));
    float e0 = __expf(r0.x - nm), e1 = __expf(r1.x - nm);
    float e2 = __expf(r2.x - nm), e3 = __expf(r3.x - nm);
    float d  = r0.y * e0 + r1.y * e1 + r2.y * e2 + r3.y * e3;
    float A0 = r0.z * e0 + r1.z * e1 + r2.z * e2 + r3.z * e3;
    float A1 = r0.w * e0 + r1.w * e1 + r2.w * e2 + r3.w * e3;
    float2 bv = *(const float2*)(bias + c0);
    float o0 = A0 / d + bv.x;
    float o1 = A1 / d + bv.y;
    o0 = o0 > 0.f ? o0 : __expf(o0) - 1.f;   // ELU
    o1 = o1 > 0.f ? o1 : __expf(o1) - 1.f;
    *(float2*)(hout + (size_t)node * 128 + c0) = make_float2(o0, o1);
  }
}

// ---------------- layer 2: block per node, 8 half-wave slots ----------------
__global__ __launch_bounds__(256) void gat2_edge(const int* __restrict__ rowptr,
                          const int* __restrict__ csrc,
                          const float* __restrict__ gl, const float* __restrict__ gr,
                          const float* __restrict__ att, const float* __restrict__ bias,
                          float* __restrict__ out) {
  int node = blockIdx.x;
  int t = threadIdx.x;
  int c = t & 31, slot = t >> 5;           // 8 slots of 32 lanes
  float attc = att[c];
  float grd = gr[(size_t)node * 32 + c];
  int start = rowptr[node], end = rowptr[node + 1];
  float m = -3.4e38f, denom = 0.f, acc = 0.f;
  int p = start + slot;
  int s = (p < end) ? csrc[p] : 0;
  float g = (p < end) ? gl[(size_t)s * 32 + c] : 0.f;
  while (p < end) {
    int pn = p + 8;
    int sn = (pn < end) ? csrc[pn] : 0;
    float gn = (pn < end) ? gl[(size_t)sn * 32 + c] : 0.f;
    float tt = g + grd; tt = tt > 0.f ? tt : NEG * tt;
    float v = attc * tt;
    v += __shfl_xor(v, 1); v += __shfl_xor(v, 2); v += __shfl_xor(v, 4);
    v += __shfl_xor(v, 8); v += __shfl_xor(v, 16);  // e, within 32-lane half-wave
    float nm = fmaxf(m, v);
    float corr = __expf(m - nm);
    float ex   = __expf(v - nm);
    denom = denom * corr + ex;
    acc   = acc * corr + ex * g;
    m = nm;
    g = gn; p = pn;
  }
  __shared__ float red[8][32][3];
  red[slot][c][0] = m; red[slot][c][1] = denom; red[slot][c][2] = acc;
  __syncthreads();
  if (t < 32) {
    float nm = -3.4e38f;
#pragma unroll
    for (int i = 0; i < 8; ++i) nm = fmaxf(nm, red[i][c][0]);
    float d = 0.f, a = 0.f;
#pragma unroll
    for (int i = 0; i < 8; ++i) {
      float e = __expf(red[i][c][0] - nm);
      d += red[i][c][1] * e;
      a += red[i][c][2] * e;
    }
    out[(size_t)node * 32 + c] = a / d + bias[c];
  }
}

extern "C" void kernel_launch(void* const* d_in, const int* in_sizes, int n_in,
                              void* d_out, int out_size, void* d_ws, size_t ws_size,
                              hipStream_t stream) {
  const float* x     = (const float*)d_in[0];
  const int*   ei    = (const int*)  d_in[1];
  const float* Wl1   = (const float*)d_in[2];
  const float* bl1   = (const float*)d_in[3];
  const float* Wr1   = (const float*)d_in[4];
  const float* br1   = (const float*)d_in[5];
  const float* att1  = (const float*)d_in[6];
  const float* bias1 = (const float*)d_in[7];
  const float* Wl2   = (const float*)d_in[8];
  const float* bl2   = (const float*)d_in[9];
  const float* Wr2   = (const float*)d_in[10];
  const float* br2   = (const float*)d_in[11];
  const float* att2  = (const float*)d_in[12];
  const float* bias2 = (const float*)d_in[13];
  float* out = (float*)d_out;

  char* w = (char*)d_ws;
  auto carve = [&](size_t bytes) {
    char* p = w;
    w += (bytes + 255) & ~(size_t)255;
    return p;
  };
  float* gl1 = (float*)carve((size_t)NNODES * 128 * 4);
  float* gr1 = (float*)carve((size_t)NNODES * 128 * 4);
  float* h   = (float*)carve((size_t)NNODES * 128 * 4);
  float* gl2 = (float*)carve((size_t)NNODES * 32 * 4);
  float* gr2 = (float*)carve((size_t)NNODES * 32 * 4);
  int* deg    = (int*)carve((size_t)NNODES * 4);
  int* fill   = (int*)carve((size_t)NNODES * 4);
  int* rowptr = (int*)carve((size_t)(NNODES + 1) * 4);
  int* csrc   = (int*)carve((size_t)ETOT * 4);

  hipMemsetAsync(deg, 0, (size_t)NNODES * 4, stream);
  hipMemsetAsync(fill, 0, (size_t)NNODES * 4, stream);

  hist_kernel<<<(ETOT + 255) / 256, 256, 0, stream>>>(ei, deg);
  scan_kernel<<<1, 1024, 0, stream>>>(deg, rowptr);
  scatter_kernel<<<(ETOT + 255) / 256, 256, 0, stream>>>(ei, rowptr, fill, csrc);

  dual_gemm<128><<<(NNODES + 15) / 16, 256, 0, stream>>>(x, Wl1, bl1, Wr1, br1, gl1, gr1);
  gat1_edge<<<NNODES, 256, 0, stream>>>(rowptr, csrc, gl1, gr1, att1, bias1, h);
  dual_gemm<32><<<(NNODES + 15) / 16, 256, 0, stream>>>(h, Wl2, bl2, Wr2, br2, gl2, gr2);
  gat2_edge<<<NNODES, 256, 0, stream>>>(rowptr, csrc, gl2, gr2, att2, bias2, out);
}

// Round 3
// 443.243 us; speedup vs baseline: 1.2151x; 1.1691x over previous
//
#include <hip/hip_runtime.h>

#define NNODES 50000
#define NEDGES 800000
#define ETOT   (NNODES + NEDGES)   // 850000 (edges + self loops)
#define NEG 0.2f

// ---------------- CSR build (by destination) ----------------
__global__ void hist_kernel(const int* __restrict__ ei, int* __restrict__ deg) {
  int i = blockIdx.x * blockDim.x + threadIdx.x;
  if (i >= ETOT) return;
  int dst = (i < NEDGES) ? ei[NEDGES + i] : (i - NEDGES);
  atomicAdd(&deg[dst], 1);
}

// 1024 threads, thread-serial chunks + shuffle scan (2 barriers total)
#define SCHUNK 49
__global__ __launch_bounds__(1024) void scan_kernel(const int* __restrict__ deg,
                                                    int* __restrict__ rowptr) {
  int t = threadIdx.x;
  int lo = t * SCHUNK;
  int hi = lo + SCHUNK; if (hi > NNODES) hi = NNODES;
  int sum = 0;
  for (int i = lo; i < hi; ++i) sum += deg[i];
  int lane = t & 63, wv = t >> 6;          // 16 waves
  int v = sum;
  for (int off = 1; off < 64; off <<= 1) {
    int u = __shfl_up(v, off);
    if (lane >= off) v += u;               // inclusive wave scan
  }
  __shared__ int wsum[16], woff[16];
  if (lane == 63) wsum[wv] = v;
  __syncthreads();
  if (t == 0) { int r = 0; for (int i = 0; i < 16; ++i) { woff[i] = r; r += wsum[i]; } }
  __syncthreads();
  int run = woff[wv] + v - sum;            // exclusive prefix for this thread's chunk
  for (int i = lo; i < hi; ++i) { rowptr[i] = run; run += deg[i]; }
  if (t == 0) rowptr[NNODES] = ETOT;
}

__global__ void scatter_kernel(const int* __restrict__ ei, const int* __restrict__ rowptr,
                               int* __restrict__ fill, int* __restrict__ csrc) {
  int i = blockIdx.x * blockDim.x + threadIdx.x;
  if (i >= ETOT) return;
  int src, dst;
  if (i < NEDGES) { src = ei[i]; dst = ei[NEDGES + i]; }
  else            { src = i - NEDGES; dst = src; }
  int pos = rowptr[dst] + atomicAdd(&fill[dst], 1);
  csrc[pos] = src;
}

// ---------------- fused dual GEMM: G1 = A@W1+b1, G2 = A@W2+b2 (K=128) ----------------
template<int MCOLS>
__global__ __launch_bounds__(256) void dual_gemm(const float* __restrict__ A,
                          const float* __restrict__ W1, const float* __restrict__ b1,
                          const float* __restrict__ W2, const float* __restrict__ b2,
                          float* __restrict__ G1, float* __restrict__ G2) {
  constexpr int K = 128;
  constexpr int ROWS = 32;
  constexpr int GROUPS = 256 / MCOLS;    // 2 (MCOLS=128) or 8 (MCOLS=32)
  constexpr int RPG = ROWS / GROUPS;     // 16 or 4
  __shared__ __align__(16) float As[ROWS][K];
  int row0 = blockIdx.x * ROWS;
  for (int idx = threadIdx.x; idx < ROWS * (K / 4); idx += 256) {
    int r = idx >> 5, k4 = idx & 31;
    int g = row0 + r;
    float4 val = (g < NNODES) ? *(const float4*)&A[(size_t)g * K + 4 * k4]
                              : make_float4(0.f, 0.f, 0.f, 0.f);
    *(float4*)&As[r][4 * k4] = val;
  }
  __syncthreads();
  int col = threadIdx.x % MCOLS;
  int grp = threadIdx.x / MCOLS;
  float acc1[RPG], acc2[RPG];
#pragma unroll
  for (int r = 0; r < RPG; ++r) { acc1[r] = 0.f; acc2[r] = 0.f; }
  for (int k4 = 0; k4 < K / 4; ++k4) {
    float w1v[4], w2v[4];
#pragma unroll
    for (int j = 0; j < 4; ++j) {
      w1v[j] = W1[(size_t)(4 * k4 + j) * MCOLS + col];
      w2v[j] = W2[(size_t)(4 * k4 + j) * MCOLS + col];
    }
#pragma unroll
    for (int r = 0; r < RPG; ++r) {
      float4 a = *(const float4*)&As[grp * RPG + r][4 * k4];
      acc1[r] = fmaf(a.x, w1v[0], acc1[r]);
      acc1[r] = fmaf(a.y, w1v[1], acc1[r]);
      acc1[r] = fmaf(a.z, w1v[2], acc1[r]);
      acc1[r] = fmaf(a.w, w1v[3], acc1[r]);
      acc2[r] = fmaf(a.x, w2v[0], acc2[r]);
      acc2[r] = fmaf(a.y, w2v[1], acc2[r]);
      acc2[r] = fmaf(a.z, w2v[2], acc2[r]);
      acc2[r] = fmaf(a.w, w2v[3], acc2[r]);
    }
  }
  float bb1 = b1[col], bb2 = b2[col];
#pragma unroll
  for (int r = 0; r < RPG; ++r) {
    int g = row0 + grp * RPG + r;
    if (g < NNODES) {
      G1[(size_t)g * MCOLS + col] = acc1[r] + bb1;
      G2[(size_t)g * MCOLS + col] = acc2[r] + bb2;
    }
  }
}

// ---------------- layer 1: wave per node, float4 lanes, 2 edges/iter ----------------
// lane = 32*half + q; q covers channels [4q,4q+4); head = q>>3 (8 lanes/head)
// half-wave h processes edges start+j+h; src indices batch-loaded 64 at a time.
__global__ __launch_bounds__(256) void gat1_edge(const int* __restrict__ rowptr,
                          const int* __restrict__ csrc,
                          const float* __restrict__ gl, const float* __restrict__ gr,
                          const float* __restrict__ att, const float* __restrict__ bias,
                          float* __restrict__ hout) {
  int node = blockIdx.x * 4 + (threadIdx.x >> 6);
  if (node >= NNODES) return;
  int lane = threadIdx.x & 63;
  int half = lane >> 5;
  int c4 = (lane & 31) * 4;
  float4 av  = *(const float4*)(att + c4);
  float4 grd = *(const float4*)(gr + (size_t)node * 128 + c4);
  int start = rowptr[node], end = rowptr[node + 1];
  float m = -3.4e38f, denom = 0.f;
  float ax = 0.f, ay = 0.f, az = 0.f, aw = 0.f;
  for (int b = start; b < end; b += 64) {
    int nb = end - b; if (nb > 64) nb = 64;
    int sidx = (lane < nb) ? csrc[b + lane] : 0;
#pragma unroll 2
    for (int j = 0; j < nb; j += 2) {
      bool pv = (j + half) < nb;
      int s = __shfl(sidx, j + half);
      float4 g = *(const float4*)(gl + (size_t)s * 128 + c4);
      float t0 = g.x + grd.x; t0 = fmaxf(t0, NEG * t0);
      float t1 = g.y + grd.y; t1 = fmaxf(t1, NEG * t1);
      float t2 = g.z + grd.z; t2 = fmaxf(t2, NEG * t2);
      float t3 = g.w + grd.w; t3 = fmaxf(t3, NEG * t3);
      float v = av.x * t0 + av.y * t1 + av.z * t2 + av.w * t3;
      v += __shfl_xor(v, 1); v += __shfl_xor(v, 2); v += __shfl_xor(v, 4);
      // v = e[head] across the 8-lane head group (per half-wave edge)
      float nm = pv ? fmaxf(m, v) : m;
      float corr = __expf(m - nm);
      float ex   = pv ? __expf(v - nm) : 0.f;
      denom = denom * corr + ex;
      ax = ax * corr + ex * g.x;
      ay = ay * corr + ex * g.y;
      az = az * corr + ex * g.z;
      aw = aw * corr + ex * g.w;
      m = nm;
    }
  }
  // combine the two half-wave slots (empty half has m=-3.4e38 -> weight 0)
  float mo = __shfl_xor(m, 32);
  float nm = fmaxf(m, mo);
  float cs = __expf(m - nm);
  float d  = denom * cs;
  ax *= cs; ay *= cs; az *= cs; aw *= cs;
  d  += __shfl_xor(d, 32);
  ax += __shfl_xor(ax, 32);
  ay += __shfl_xor(ay, 32);
  az += __shfl_xor(az, 32);
  aw += __shfl_xor(aw, 32);
  if (half == 0) {
    float4 bv = *(const float4*)(bias + c4);
    float inv = 1.f / d;
    float o0 = ax * inv + bv.x;
    float o1 = ay * inv + bv.y;
    float o2 = az * inv + bv.z;
    float o3 = aw * inv + bv.w;
    o0 = o0 > 0.f ? o0 : __expf(o0) - 1.f;   // ELU
    o1 = o1 > 0.f ? o1 : __expf(o1) - 1.f;
    o2 = o2 > 0.f ? o2 : __expf(o2) - 1.f;
    o3 = o3 > 0.f ? o3 : __expf(o3) - 1.f;
    *(float4*)(hout + (size_t)node * 128 + c4) = make_float4(o0, o1, o2, o3);
  }
}

// ---------------- layer 2: wave per node, 1 ch/lane, 2 edges/iter ----------------
__global__ __launch_bounds__(256) void gat2_edge(const int* __restrict__ rowptr,
                          const int* __restrict__ csrc,
                          const float* __restrict__ gl, const float* __restrict__ gr,
                          const float* __restrict__ att, const float* __restrict__ bias,
                          float* __restrict__ out) {
  int node = blockIdx.x * 4 + (threadIdx.x >> 6);
  if (node >= NNODES) return;
  int lane = threadIdx.x & 63;
  int half = lane >> 5;
  int c = lane & 31;
  float attc = att[c];
  float grd = gr[(size_t)node * 32 + c];
  int start = rowptr[node], end = rowptr[node + 1];
  float m = -3.4e38f, denom = 0.f, acc = 0.f;
  for (int b = start; b < end; b += 64) {
    int nb = end - b; if (nb > 64) nb = 64;
    int sidx = (lane < nb) ? csrc[b + lane] : 0;
#pragma unroll 2
    for (int j = 0; j < nb; j += 2) {
      bool pv = (j + half) < nb;
      int s = __shfl(sidx, j + half);
      float g = gl[(size_t)s * 32 + c];
      float t = g + grd; t = fmaxf(t, NEG * t);
      float v = attc * t;
      v += __shfl_xor(v, 1); v += __shfl_xor(v, 2); v += __shfl_xor(v, 4);
      v += __shfl_xor(v, 8); v += __shfl_xor(v, 16);   // e within the 32-lane half
      float nm = pv ? fmaxf(m, v) : m;
      float corr = __expf(m - nm);
      float ex   = pv ? __expf(v - nm) : 0.f;
      denom = denom * corr + ex;
      acc   = acc * corr + ex * g;
      m = nm;
    }
  }
  float mo = __shfl_xor(m, 32);
  float nm = fmaxf(m, mo);
  float cs = __expf(m - nm);
  float d  = denom * cs;
  float a  = acc * cs;
  d += __shfl_xor(d, 32);
  a += __shfl_xor(a, 32);
  if (half == 0) out[(size_t)node * 32 + c] = a / d + bias[c];
}

extern "C" void kernel_launch(void* const* d_in, const int* in_sizes, int n_in,
                              void* d_out, int out_size, void* d_ws, size_t ws_size,
                              hipStream_t stream) {
  const float* x     = (const float*)d_in[0];
  const int*   ei    = (const int*)  d_in[1];
  const float* Wl1   = (const float*)d_in[2];
  const float* bl1   = (const float*)d_in[3];
  const float* Wr1   = (const float*)d_in[4];
  const float* br1   = (const float*)d_in[5];
  const float* att1  = (const float*)d_in[6];
  const float* bias1 = (const float*)d_in[7];
  const float* Wl2   = (const float*)d_in[8];
  const float* bl2   = (const float*)d_in[9];
  const float* Wr2   = (const float*)d_in[10];
  const float* br2   = (const float*)d_in[11];
  const float* att2  = (const float*)d_in[12];
  const float* bias2 = (const float*)d_in[13];
  float* out = (float*)d_out;

  char* w = (char*)d_ws;
  auto carve = [&](size_t bytes) {
    char* p = w;
    w += (bytes + 255) & ~(size_t)255;
    return p;
  };
  float* gl1 = (float*)carve((size_t)NNODES * 128 * 4);
  float* gr1 = (float*)carve((size_t)NNODES * 128 * 4);
  float* h   = (float*)carve((size_t)NNODES * 128 * 4);
  float* gl2 = (float*)carve((size_t)NNODES * 32 * 4);
  float* gr2 = (float*)carve((size_t)NNODES * 32 * 4);
  int* deg    = (int*)carve((size_t)NNODES * 4);
  int* fill   = (int*)carve((size_t)NNODES * 4);
  int* rowptr = (int*)carve((size_t)(NNODES + 1) * 4);
  int* csrc   = (int*)carve((size_t)ETOT * 4);

  hipMemsetAsync(deg, 0, (size_t)NNODES * 4, stream);
  hipMemsetAsync(fill, 0, (size_t)NNODES * 4, stream);

  hist_kernel<<<(ETOT + 255) / 256, 256, 0, stream>>>(ei, deg);
  scan_kernel<<<1, 1024, 0, stream>>>(deg, rowptr);
  scatter_kernel<<<(ETOT + 255) / 256, 256, 0, stream>>>(ei, rowptr, fill, csrc);

  dual_gemm<128><<<(NNODES + 31) / 32, 256, 0, stream>>>(x, Wl1, bl1, Wr1, br1, gl1, gr1);
  gat1_edge<<<(NNODES + 3) / 4, 256, 0, stream>>>(rowptr, csrc, gl1, gr1, att1, bias1, h);
  dual_gemm<32><<<(NNODES + 31) / 32, 256, 0, stream>>>(h, Wl2, bl2, Wr2, br2, gl2, gr2);
  gat2_edge<<<(NNODES + 3) / 4, 256, 0, stream>>>(rowptr, csrc, gl2, gr2, att2, bias2, out);
}

// Round 4
// 371.003 us; speedup vs baseline: 1.4517x; 1.1947x over previous
//
#include <hip/hip_runtime.h>

#define NNODES 50000
#define NEDGES 800000
#define ETOT   (NNODES + NEDGES)   // 850000 (edges + self loops)
#define NEG 0.2f
#define SBLK 256
#define NSB ((NNODES + SBLK - 1) / SBLK)   // 196 scan blocks

// ---------------- CSR build (by destination) ----------------
__global__ void hist_kernel(const int* __restrict__ ei, int* __restrict__ deg) {
  int i = blockIdx.x * blockDim.x + threadIdx.x;
  if (i >= ETOT) return;
  int dst = (i < NEDGES) ? ei[NEDGES + i] : (i - NEDGES);
  atomicAdd(&deg[dst], 1);
}

// phase 1: per-block sums (coalesced, shuffle reduce)
__global__ __launch_bounds__(256) void scan_phase1(const int* __restrict__ deg,
                                                   int* __restrict__ bsum) {
  int i = blockIdx.x * SBLK + threadIdx.x;
  int v = (i < NNODES) ? deg[i] : 0;
  v += __shfl_xor(v, 1);  v += __shfl_xor(v, 2);  v += __shfl_xor(v, 4);
  v += __shfl_xor(v, 8);  v += __shfl_xor(v, 16); v += __shfl_xor(v, 32);
  __shared__ int ws[4];
  if ((threadIdx.x & 63) == 0) ws[threadIdx.x >> 6] = v;
  __syncthreads();
  if (threadIdx.x == 0) bsum[blockIdx.x] = ws[0] + ws[1] + ws[2] + ws[3];
}

// phase 2: single small block exclusive-scans the 196 block sums in place
__global__ __launch_bounds__(256) void scan_phase2(int* __restrict__ bsum) {
  int t = threadIdx.x;
  int v = (t < NSB) ? bsum[t] : 0;
  int lane = t & 63, wv = t >> 6;
  int s = v;
  for (int off = 1; off < 64; off <<= 1) {
    int u = __shfl_up(s, off);
    if (lane >= off) s += u;
  }
  __shared__ int ws[4];
  if (lane == 63) ws[wv] = s;
  __syncthreads();
  int add = 0;
  for (int i = 0; i < wv; ++i) add += ws[i];
  if (t < NSB) bsum[t] = add + s - v;     // exclusive prefix of block sums
}

// phase 3: per-block exclusive scan + block offset -> rowptr (coalesced)
__global__ __launch_bounds__(256) void scan_phase3(const int* __restrict__ deg,
                                                   const int* __restrict__ bsum,
                                                   int* __restrict__ rowptr) {
  int i = blockIdx.x * SBLK + threadIdx.x;
  int v = (i < NNODES) ? deg[i] : 0;
  int lane = threadIdx.x & 63, wv = threadIdx.x >> 6;
  int s = v;
  for (int off = 1; off < 64; off <<= 1) {
    int u = __shfl_up(s, off);
    if (lane >= off) s += u;
  }
  __shared__ int ws[4];
  if (lane == 63) ws[wv] = s;
  __syncthreads();
  int add = bsum[blockIdx.x];
  for (int k = 0; k < wv; ++k) add += ws[k];
  if (i < NNODES) rowptr[i] = add + s - v;
  if (i == 0) rowptr[NNODES] = ETOT;
}

__global__ void scatter_kernel(const int* __restrict__ ei, const int* __restrict__ rowptr,
                               int* __restrict__ fill, int* __restrict__ csrc) {
  int i = blockIdx.x * blockDim.x + threadIdx.x;
  if (i >= ETOT) return;
  int src, dst;
  if (i < NEDGES) { src = ei[i]; dst = ei[NEDGES + i]; }
  else            { src = i - NEDGES; dst = src; }
  int pos = rowptr[dst] + atomicAdd(&fill[dst], 1);
  csrc[pos] = src;
}

// ---------------- fused dual GEMM: G1 = A@W1+b1, G2 = A@W2+b2 (K=128) ----------------
template<int MCOLS>
__global__ __launch_bounds__(256) void dual_gemm(const float* __restrict__ A,
                          const float* __restrict__ W1, const float* __restrict__ b1,
                          const float* __restrict__ W2, const float* __restrict__ b2,
                          float* __restrict__ G1, float* __restrict__ G2) {
  constexpr int K = 128;
  constexpr int ROWS = 32;
  constexpr int GROUPS = 256 / MCOLS;    // 2 (MCOLS=128) or 8 (MCOLS=32)
  constexpr int RPG = ROWS / GROUPS;     // 16 or 4
  __shared__ __align__(16) float As[ROWS][K];
  int row0 = blockIdx.x * ROWS;
  for (int idx = threadIdx.x; idx < ROWS * (K / 4); idx += 256) {
    int r = idx >> 5, k4 = idx & 31;
    int g = row0 + r;
    float4 val = (g < NNODES) ? *(const float4*)&A[(size_t)g * K + 4 * k4]
                              : make_float4(0.f, 0.f, 0.f, 0.f);
    *(float4*)&As[r][4 * k4] = val;
  }
  __syncthreads();
  int col = threadIdx.x % MCOLS;
  int grp = threadIdx.x / MCOLS;
  float acc1[RPG], acc2[RPG];
#pragma unroll
  for (int r = 0; r < RPG; ++r) { acc1[r] = 0.f; acc2[r] = 0.f; }
  for (int k4 = 0; k4 < K / 4; ++k4) {
    float w1v[4], w2v[4];
#pragma unroll
    for (int j = 0; j < 4; ++j) {
      w1v[j] = W1[(size_t)(4 * k4 + j) * MCOLS + col];
      w2v[j] = W2[(size_t)(4 * k4 + j) * MCOLS + col];
    }
#pragma unroll
    for (int r = 0; r < RPG; ++r) {
      float4 a = *(const float4*)&As[grp * RPG + r][4 * k4];
      acc1[r] = fmaf(a.x, w1v[0], acc1[r]);
      acc1[r] = fmaf(a.y, w1v[1], acc1[r]);
      acc1[r] = fmaf(a.z, w1v[2], acc1[r]);
      acc1[r] = fmaf(a.w, w1v[3], acc1[r]);
      acc2[r] = fmaf(a.x, w2v[0], acc2[r]);
      acc2[r] = fmaf(a.y, w2v[1], acc2[r]);
      acc2[r] = fmaf(a.z, w2v[2], acc2[r]);
      acc2[r] = fmaf(a.w, w2v[3], acc2[r]);
    }
  }
  float bb1 = b1[col], bb2 = b2[col];
#pragma unroll
  for (int r = 0; r < RPG; ++r) {
    int g = row0 + grp * RPG + r;
    if (g < NNODES) {
      G1[(size_t)g * MCOLS + col] = acc1[r] + bb1;
      G2[(size_t)g * MCOLS + col] = acc2[r] + bb2;
    }
  }
}

// ---------------- layer 1: wave per node, float4 lanes, 2 edges/iter ----------------
__global__ __launch_bounds__(256) void gat1_edge(const int* __restrict__ rowptr,
                          const int* __restrict__ csrc,
                          const float* __restrict__ gl, const float* __restrict__ gr,
                          const float* __restrict__ att, const float* __restrict__ bias,
                          float* __restrict__ hout) {
  int node = blockIdx.x * 4 + (threadIdx.x >> 6);
  if (node >= NNODES) return;
  int lane = threadIdx.x & 63;
  int half = lane >> 5;
  int c4 = (lane & 31) * 4;
  float4 av  = *(const float4*)(att + c4);
  float4 grd = *(const float4*)(gr + (size_t)node * 128 + c4);
  int start = rowptr[node], end = rowptr[node + 1];
  float m = -3.4e38f, denom = 0.f;
  float ax = 0.f, ay = 0.f, az = 0.f, aw = 0.f;
  for (int b = start; b < end; b += 64) {
    int nb = end - b; if (nb > 64) nb = 64;
    int sidx = (lane < nb) ? csrc[b + lane] : 0;
#pragma unroll 2
    for (int j = 0; j < nb; j += 2) {
      bool pv = (j + half) < nb;
      int s = __shfl(sidx, j + half);
      float4 g = *(const float4*)(gl + (size_t)s * 128 + c4);
      float t0 = g.x + grd.x; t0 = fmaxf(t0, NEG * t0);
      float t1 = g.y + grd.y; t1 = fmaxf(t1, NEG * t1);
      float t2 = g.z + grd.z; t2 = fmaxf(t2, NEG * t2);
      float t3 = g.w + grd.w; t3 = fmaxf(t3, NEG * t3);
      float v = av.x * t0 + av.y * t1 + av.z * t2 + av.w * t3;
      v += __shfl_xor(v, 1); v += __shfl_xor(v, 2); v += __shfl_xor(v, 4);
      float nm = pv ? fmaxf(m, v) : m;
      float corr = __expf(m - nm);
      float ex   = pv ? __expf(v - nm) : 0.f;
      denom = denom * corr + ex;
      ax = ax * corr + ex * g.x;
      ay = ay * corr + ex * g.y;
      az = az * corr + ex * g.z;
      aw = aw * corr + ex * g.w;
      m = nm;
    }
  }
  float mo = __shfl_xor(m, 32);
  float nm = fmaxf(m, mo);
  float cs = __expf(m - nm);
  float d  = denom * cs;
  ax *= cs; ay *= cs; az *= cs; aw *= cs;
  d  += __shfl_xor(d, 32);
  ax += __shfl_xor(ax, 32);
  ay += __shfl_xor(ay, 32);
  az += __shfl_xor(az, 32);
  aw += __shfl_xor(aw, 32);
  if (half == 0) {
    float4 bv = *(const float4*)(bias + c4);
    float inv = 1.f / d;
    float o0 = ax * inv + bv.x;
    float o1 = ay * inv + bv.y;
    float o2 = az * inv + bv.z;
    float o3 = aw * inv + bv.w;
    o0 = o0 > 0.f ? o0 : __expf(o0) - 1.f;   // ELU
    o1 = o1 > 0.f ? o1 : __expf(o1) - 1.f;
    o2 = o2 > 0.f ? o2 : __expf(o2) - 1.f;
    o3 = o3 > 0.f ? o3 : __expf(o3) - 1.f;
    *(float4*)(hout + (size_t)node * 128 + c4) = make_float4(o0, o1, o2, o3);
  }
}

// ---------------- layer 2: wave per node, 1 ch/lane, 2 edges/iter ----------------
__global__ __launch_bounds__(256) void gat2_edge(const int* __restrict__ rowptr,
                          const int* __restrict__ csrc,
                          const float* __restrict__ gl, const float* __restrict__ gr,
                          const float* __restrict__ att, const float* __restrict__ bias,
                          float* __restrict__ out) {
  int node = blockIdx.x * 4 + (threadIdx.x >> 6);
  if (node >= NNODES) return;
  int lane = threadIdx.x & 63;
  int half = lane >> 5;
  int c = lane & 31;
  float attc = att[c];
  float grd = gr[(size_t)node * 32 + c];
  int start = rowptr[node], end = rowptr[node + 1];
  float m = -3.4e38f, denom = 0.f, acc = 0.f;
  for (int b = start; b < end; b += 64) {
    int nb = end - b; if (nb > 64) nb = 64;
    int sidx = (lane < nb) ? csrc[b + lane] : 0;
#pragma unroll 2
    for (int j = 0; j < nb; j += 2) {
      bool pv = (j + half) < nb;
      int s = __shfl(sidx, j + half);
      float g = gl[(size_t)s * 32 + c];
      float t = g + grd; t = fmaxf(t, NEG * t);
      float v = attc * t;
      v += __shfl_xor(v, 1); v += __shfl_xor(v, 2); v += __shfl_xor(v, 4);
      v += __shfl_xor(v, 8); v += __shfl_xor(v, 16);
      float nm = pv ? fmaxf(m, v) : m;
      float corr = __expf(m - nm);
      float ex   = pv ? __expf(v - nm) : 0.f;
      denom = denom * corr + ex;
      acc   = acc * corr + ex * g;
      m = nm;
    }
  }
  float mo = __shfl_xor(m, 32);
  float nm = fmaxf(m, mo);
  float cs = __expf(m - nm);
  float d  = denom * cs;
  float a  = acc * cs;
  d += __shfl_xor(d, 32);
  a += __shfl_xor(a, 32);
  if (half == 0) out[(size_t)node * 32 + c] = a / d + bias[c];
}

extern "C" void kernel_launch(void* const* d_in, const int* in_sizes, int n_in,
                              void* d_out, int out_size, void* d_ws, size_t ws_size,
                              hipStream_t stream) {
  const float* x     = (const float*)d_in[0];
  const int*   ei    = (const int*)  d_in[1];
  const float* Wl1   = (const float*)d_in[2];
  const float* bl1   = (const float*)d_in[3];
  const float* Wr1   = (const float*)d_in[4];
  const float* br1   = (const float*)d_in[5];
  const float* att1  = (const float*)d_in[6];
  const float* bias1 = (const float*)d_in[7];
  const float* Wl2   = (const float*)d_in[8];
  const float* bl2   = (const float*)d_in[9];
  const float* Wr2   = (const float*)d_in[10];
  const float* br2   = (const float*)d_in[11];
  const float* att2  = (const float*)d_in[12];
  const float* bias2 = (const float*)d_in[13];
  float* out = (float*)d_out;

  char* w = (char*)d_ws;
  auto carve = [&](size_t bytes) {
    char* p = w;
    w += (bytes + 255) & ~(size_t)255;
    return p;
  };
  float* gl1 = (float*)carve((size_t)NNODES * 128 * 4);
  float* gr1 = (float*)carve((size_t)NNODES * 128 * 4);
  float* h   = (float*)carve((size_t)NNODES * 128 * 4);
  float* gl2 = (float*)carve((size_t)NNODES * 32 * 4);
  float* gr2 = (float*)carve((size_t)NNODES * 32 * 4);
  int* degfill = (int*)carve((size_t)2 * NNODES * 4);   // deg | fill, one memset
  int* deg  = degfill;
  int* fill = degfill + NNODES;
  int* rowptr = (int*)carve((size_t)(NNODES + 1) * 4);
  int* bsum   = (int*)carve((size_t)NSB * 4);
  int* csrc   = (int*)carve((size_t)ETOT * 4);

  hipMemsetAsync(degfill, 0, (size_t)2 * NNODES * 4, stream);

  hist_kernel<<<(ETOT + 255) / 256, 256, 0, stream>>>(ei, deg);
  scan_phase1<<<NSB, 256, 0, stream>>>(deg, bsum);
  scan_phase2<<<1, 256, 0, stream>>>(bsum);
  scan_phase3<<<NSB, 256, 0, stream>>>(deg, bsum, rowptr);
  scatter_kernel<<<(ETOT + 255) / 256, 256, 0, stream>>>(ei, rowptr, fill, csrc);

  dual_gemm<128><<<(NNODES + 31) / 32, 256, 0, stream>>>(x, Wl1, bl1, Wr1, br1, gl1, gr1);
  gat1_edge<<<(NNODES + 3) / 4, 256, 0, stream>>>(rowptr, csrc, gl1, gr1, att1, bias1, h);
  dual_gemm<32><<<(NNODES + 31) / 32, 256, 0, stream>>>(h, Wl2, bl2, Wr2, br2, gl2, gr2);
  gat2_edge<<<(NNODES + 3) / 4, 256, 0, stream>>>(rowptr, csrc, gl2, gr2, att2, bias2, out);
}